// Round 15
// baseline (7411.126 us; speedup 1.0000x reference)
//
#include <hip/hip_runtime.h>
#include <hip/hip_bf16.h>
#include <hip/hip_fp16.h>
#include <stdint.h>

#define BB  256
#define TT  512
#define FF  8
#define HH  256
#define H4  1024
#define DEC 35
#define MW  16

typedef __attribute__((ext_vector_type(8))) short short8v;
typedef __attribute__((ext_vector_type(4))) float f32x4;

__device__ __forceinline__ unsigned short f2bf(float x) {
    unsigned u = __float_as_uint(x);
    u += 0x7fffu + ((u >> 16) & 1u);          // RNE
    return (unsigned short)(u >> 16);
}
__device__ __forceinline__ float bf2f(unsigned s) { return __uint_as_float(s << 16); }
__device__ __forceinline__ float sigf(float x) {
    x = fminf(fmaxf(x, -30.f), 30.f);
    return 1.0f / (1.0f + __expf(-x));
}
__device__ __forceinline__ float tanh_(float x) {
    x = fminf(fmaxf(x, -15.f), 15.f);
    float e = __expf(2.0f * x);
    return (e - 1.0f) / (e + 1.0f);
}

// ===================== prep kernels (proven rounds 12-13) =====================

__global__ void prep_consts(const float* __restrict__ W_pe, const float* __restrict__ b_pe,
                            const float* __restrict__ embed, const float* __restrict__ W_x,
                            const float* __restrict__ b_lstm,
                            const float* __restrict__ bn_gamma, const float* __restrict__ bn_beta,
                            const float* __restrict__ bn_mean, const float* __restrict__ bn_var,
                            float* __restrict__ Wpx32, float* __restrict__ zbias,
                            float* __restrict__ zdec0) {
    int n = blockIdx.x * 256 + threadIdx.x;
    float acc[FF];
    #pragma unroll
    for (int f = 0; f < FF; ++f) acc[f] = 0.f;
    float bsum = 0.f, dsum = 0.f;
    for (int m = 0; m < HH; ++m) {
        float wx = W_x[m * H4 + n];
        #pragma unroll
        for (int f = 0; f < FF; ++f) acc[f] = fmaf(W_pe[f * HH + m], wx, acc[f]);
        bsum = fmaf(b_pe[m], wx, bsum);
        dsum = fmaf(embed[m], wx, dsum);
    }
    float zb = b_lstm[n] + bsum;
    #pragma unroll
    for (int f = 0; f < FF; ++f) {
        float s  = bn_gamma[f] * rsqrtf(bn_var[f] + 1e-3f);
        float sh = bn_beta[f] - bn_mean[f] * s;
        Wpx32[f * H4 + n] = s * acc[f];
        zb = fmaf(sh, acc[f], zb);
    }
    zbias[n] = zb;
    zdec0[n] = b_lstm[n] + dsum;
}

// B-frags: frag[(nt*8+kc)*64+ln][j] = W[k = kc*32 + 8*(ln>>4) + j][nt*16 + (ln&15)]
__global__ void prep_wfrag(const float* __restrict__ W_x, const float* __restrict__ W_h,
                           short8v* __restrict__ whf, short8v* __restrict__ wsf) {
    int nt = blockIdx.x >> 3, kc = blockIdx.x & 7, ln = threadIdx.x;
    int n = nt * 16 + (ln & 15), q = ln >> 4;
    short8v vh, vs;
    #pragma unroll
    for (int j = 0; j < 8; ++j) {
        int k = kc * 32 + q * 8 + j;
        float wh = W_h[k * H4 + n], wx = W_x[k * H4 + n];
        vh[j] = (short)f2bf(wh);
        vs[j] = (short)f2bf(wx + wh);
    }
    whf[blockIdx.x * 64 + ln] = vh;
    wsf[blockIdx.x * 64 + ln] = vs;
}

// zx B-frags: K=32 packed [Whi|Whi|Wlo|Wlo]; pairs with A=[ph|pl|ph|pl]
// -> one MFMA = (ph+pl)*(Whi+Wlo), fp32-accurate (round-12-proven).
__global__ void prep_wpxf(const float* __restrict__ Wpx32, short8v* __restrict__ wpxf) {
    int nt = blockIdx.x, ln = threadIdx.x;
    int n = nt * 16 + (ln & 15), qq = ln >> 4;
    short8v v;
    #pragma unroll
    for (int j = 0; j < 8; ++j) {
        float wv = Wpx32[j * H4 + n];
        unsigned short hi = f2bf(wv);
        v[j] = (qq < 2) ? (short)hi : (short)f2bf(wv - bf2f(hi));
    }
    wpxf[nt * 64 + ln] = v;
}

// ===================== main recurrent kernel: 4-way unit split =====================
// 64 WGs x 256 thr (4 waves). Group gb = bx>>2 (16 batches); member jj = bx&3
// owns units [64jj, 64jj+64). Wave w owns unit-tile ut = 4jj+w: col-tiles
// ntv[gg] = gg*16+ut (the 4 gates of its 16 units) -> gate math lane-local.
// Per-WG stream 128KB/step (4x less than r12's 512KB/CU -- the measured
// serial-sum bottleneck). h exchanged per step via global hx + device-scope
// atomic counter (cross-XCD safe per G12/G16). PLAIN LAUNCH: 64 WGs on 256
// CUs are co-resident by CAPACITY (grid <= CU count; spinning WGs occupy
// distinct CUs and cannot block dispatch) -- no cooperative launch, which is
// unsafe under graph capture (round-14 container death suspect).
// 256-thr WG => 256-VGPR budget: no spill. Math order per tile identical to
// r12 -> absmax must repeat 0.0078125.
__global__ __launch_bounds__(256) void lstm_rec12(
    const short8v* __restrict__ whf, const short8v* __restrict__ wsf,
    const short8v* __restrict__ wpxf,
    const float* __restrict__ pulse,
    const float* __restrict__ zbias, const float* __restrict__ zdec0,
    const float* __restrict__ blstm,
    const float* __restrict__ W_mlp, const float* __restrict__ b_mlp,
    const float* __restrict__ scale_w, const float* __restrict__ scale_b,
    unsigned short* __restrict__ hx, int* __restrict__ ctr,
    float* __restrict__ out) {
    __shared__ short8v ldsHI[512];   // full 256-unit h hi A-frags (8 kc x 64)
    __shared__ short8v ldsLO[512];
    __shared__ float sWmlp[HH * 2];
    __shared__ float sm[6];

    const int tid = threadIdx.x, bx = blockIdx.x;
    const int gb = bx >> 2, jj = bx & 3;
    const int w = tid >> 6, ln = tid & 63;
    const int col = ln & 15, q = ln >> 4;
    const int ut = jj * 4 + w;           // this wave's unit-tile (0..15)

    int ntv[4];
    #pragma unroll
    for (int gg = 0; gg < 4; ++gg) ntv[gg] = gg * 16 + ut;

    unsigned short* hxg = hx + (size_t)gb * 8192;   // 4096 hi + 4096 lo shorts

    // ---- init ----
    sWmlp[tid] = W_mlp[tid];
    sWmlp[256 + tid] = W_mlp[256 + tid];
    if (tid < 2) { sm[tid] = b_mlp[tid]; sm[2 + tid] = scale_w[tid]; sm[4 + tid] = scale_b[tid]; }
    {
        short8v zz = {};
        ldsHI[tid] = zz; ldsHI[256 + tid] = zz;
        ldsLO[tid] = zz; ldsLO[256 + tid] = zz;
    }
    short8v wpxr[4];
    float zb[4], zd0[4], bl[4];
    #pragma unroll
    for (int gg = 0; gg < 4; ++gg) {
        wpxr[gg] = wpxf[(size_t)ntv[gg] * 64 + ln];
        int n = ntv[gg] * 16 + col;
        zb[gg]  = zbias[n];
        zd0[gg] = zdec0[n];
        bl[gg]  = blstm[n];
    }
    float c[4];
    #pragma unroll
    for (int i = 0; i < 4; ++i) c[i] = 0.f;

    const float* ppt = pulse + ((size_t)(gb * MW + col) * TT) * FF;  // A row = batch
    const int lohalf = q & 1;
    int sync_no = 0;
    __syncthreads();

    // 4-tile stream chain, 2-slice rolling dbuf (round-11-proven shape)
#define CHAIN4(SRC) do {                                                        \
        short8v ws0[4], ws1[4];                                                 \
        _Pragma("unroll")                                                       \
        for (int i = 0; i < 4; ++i) {                                           \
            ws0[i] = (SRC)[(size_t)(ntv[i] * 8 + 0) * 64 + ln];                 \
            ws1[i] = (SRC)[(size_t)(ntv[i] * 8 + 1) * 64 + ln];                 \
        }                                                                       \
        _Pragma("unroll")                                                       \
        for (int kc = 0; kc < 8; ++kc) {                                        \
            short8v ah = ldsHI[kc * 64 + ln];                                   \
            short8v al = ldsLO[kc * 64 + ln];                                   \
            if ((kc & 1) == 0) {                                                \
                _Pragma("unroll")                                               \
                for (int i = 0; i < 4; ++i) {                                   \
                    acc[i] = __builtin_amdgcn_mfma_f32_16x16x32_bf16(ah, ws0[i], acc[i], 0, 0, 0); \
                    acc[i] = __builtin_amdgcn_mfma_f32_16x16x32_bf16(al, ws0[i], acc[i], 0, 0, 0); \
                    if (kc + 2 < 8) ws0[i] = (SRC)[(size_t)(ntv[i] * 8 + kc + 2) * 64 + ln]; \
                }                                                               \
            } else {                                                            \
                _Pragma("unroll")                                               \
                for (int i = 0; i < 4; ++i) {                                   \
                    acc[i] = __builtin_amdgcn_mfma_f32_16x16x32_bf16(ah, ws1[i], acc[i], 0, 0, 0); \
                    acc[i] = __builtin_amdgcn_mfma_f32_16x16x32_bf16(al, ws1[i], acc[i], 0, 0, 0); \
                    if (kc + 2 < 8) ws1[i] = (SRC)[(size_t)(ntv[i] * 8 + kc + 2) * 64 + ln]; \
                }                                                               \
            }                                                                   \
        }                                                                       \
    } while (0)

    // gates -> h; write split-h to the group's global exchange buffer.
    // ad(u,b) = (u>>5)*512 + ((u>>3)&3)*128 + b*8 + (u&7)  [verified layout]
#define GATES_STORE() do {                                                      \
        _Pragma("unroll")                                                       \
        for (int r = 0; r < 4; ++r) {                                           \
            float cc = sigf(acc[1][r]) * c[r] + sigf(acc[0][r]) * tanh_(acc[2][r]); \
            c[r] = cc;                                                          \
            float hh = sigf(acc[3][r]) * tanh_(cc);                             \
            unsigned short hi = f2bf(hh);                                       \
            float lo = hh - bf2f(hi);                                           \
            int u = ut * 16 + col, b = 4 * q + r;                               \
            int ad = (u >> 5) * 512 + ((u >> 3) & 3) * 128 + b * 8 + (u & 7);   \
            hxg[ad] = hi;                                                       \
            hxg[4096 + ad] = f2bf(lo);                                          \
        }                                                                       \
    } while (0)

    // release(all writes) -> group barrier via device-scope counter -> acquire
    // -> stage full h-frags into LDS
#define EXCHANGE() do {                                                         \
        __threadfence();                                                        \
        __syncthreads();                                                        \
        ++sync_no;                                                              \
        if (tid == 0) {                                                         \
            atomicAdd(ctr + gb, 1);                                             \
            while (atomicAdd(ctr + gb, 0) < 4 * sync_no)                        \
                __builtin_amdgcn_s_sleep(1);                                    \
        }                                                                       \
        __syncthreads();                                                        \
        __threadfence();                                                        \
        const short8v* hxv = (const short8v*)hxg;                               \
        ldsHI[tid]       = hxv[tid];                                            \
        ldsHI[256 + tid] = hxv[256 + tid];                                      \
        ldsLO[tid]       = hxv[512 + tid];                                      \
        ldsLO[256 + tid] = hxv[768 + tid];                                      \
        __syncthreads();                                                        \
    } while (0)

    // ---- encoder: 512 steps ----
    for (int t = 0; t < TT; ++t) {
        float4 p0 = ((const float4*)ppt)[0];
        float4 p1 = ((const float4*)ppt)[1];
        ppt += FF;
        float pv[8];
        pv[0] = p0.x; pv[1] = p0.y; pv[2] = p0.z; pv[3] = p0.w;
        pv[4] = p1.x; pv[5] = p1.y; pv[6] = p1.z; pv[7] = p1.w;
        short8v apack;
        #pragma unroll
        for (int j = 0; j < 8; ++j) {
            unsigned short hi = f2bf(pv[j]);
            apack[j] = lohalf ? (short)f2bf(pv[j] - bf2f(hi)) : (short)hi;
        }
        f32x4 acc[4];
        #pragma unroll
        for (int gg = 0; gg < 4; ++gg) {
            f32x4 av; av[0] = zb[gg]; av[1] = zb[gg]; av[2] = zb[gg]; av[3] = zb[gg];
            acc[gg] = __builtin_amdgcn_mfma_f32_16x16x32_bf16(apack, wpxr[gg], av, 0, 0, 0);
        }
        CHAIN4(whf);
        GATES_STORE();
        EXCHANGE();
    }

    // ---- decoder: 35 steps ----
    for (int s = 0; s < DEC; ++s) {
        f32x4 acc[4];
        if (s == 0) {
            #pragma unroll
            for (int gg = 0; gg < 4; ++gg) {
                f32x4 av; av[0] = zd0[gg]; av[1] = zd0[gg]; av[2] = zd0[gg]; av[3] = zd0[gg];
                acc[gg] = av;
            }
            CHAIN4(whf);
        } else {
            #pragma unroll
            for (int gg = 0; gg < 4; ++gg) {
                f32x4 av; av[0] = bl[gg]; av[1] = bl[gg]; av[2] = bl[gg]; av[3] = bl[gg];
                acc[gg] = av;
            }
            CHAIN4(wsf);
        }
        GATES_STORE();
        EXCHANGE();

        // MLP head: leader WG only, reads the freshly staged LDS h-frags
        if (jj == 0) {
            const unsigned short* hHIs = (const unsigned short*)ldsHI;
            const unsigned short* hLOs = (const unsigned short*)ldsLO;
            int m = tid >> 4, j2 = (tid >> 3) & 1, uc = tid & 7;
            float p2 = 0.f;
            #pragma unroll
            for (int i = 0; i < 32; ++i) {
                int u = i * 8 + uc;
                int ad = (u >> 5) * 512 + ((u >> 3) & 3) * 128 + m * 8 + (u & 7);
                float hv = bf2f(hHIs[ad]) + bf2f(hLOs[ad]);
                p2 = fmaf(hv, sWmlp[u * 2 + j2], p2);
            }
            p2 += __shfl_down(p2, 4, 8);
            p2 += __shfl_down(p2, 2, 8);
            p2 += __shfl_down(p2, 1, 8);
            if (uc == 0) {
                float pr = p2 + sm[j2];
                out[((size_t)(gb * MW + m) * DEC + s) * 2 + j2] = pr * sm[2 + j2] + sm[4 + j2];
            }
        }
    }
#undef CHAIN4
#undef GATES_STORE
#undef EXCHANGE
}

// ===================== fallback (round-2, proven) =====================
__global__ void prep_weights(const float* __restrict__ Wx, const float* __restrict__ Wh,
                             __hip_bfloat16* __restrict__ wxb,
                             __hip_bfloat16* __restrict__ whb,
                             __hip_bfloat16* __restrict__ wsb) {
    int i = blockIdx.x * 256 + threadIdx.x;
    if (i < HH * H4) {
        float x = Wx[i], h = Wh[i];
        wxb[i] = __float2bfloat16(x);
        whb[i] = __float2bfloat16(h);
        wsb[i] = __float2bfloat16(x + h);
    }
}

template<bool BF16W>
__device__ __forceinline__ void matvec2(const void* __restrict__ W,
                                        const float* __restrict__ vec,
                                        int tid, float& z0, float& z1) {
    if constexpr (BF16W) {
        const uint32_t* Wp = (const uint32_t*)W;
        #pragma unroll 8
        for (int k = 0; k < HH; ++k) {
            uint32_t w = Wp[(size_t)k * (H4 / 2) + tid];
            float s = vec[k];
            union { uint32_t u; float f; } lo, hi;
            lo.u = w << 16;
            hi.u = w & 0xffff0000u;
            z0 = fmaf(s, lo.f, z0);
            z1 = fmaf(s, hi.f, z1);
        }
    } else {
        const float2* Wp = (const float2*)W;
        #pragma unroll 8
        for (int k = 0; k < HH; ++k) {
            float2 w = Wp[(size_t)k * (H4 / 2) + tid];
            float s = vec[k];
            z0 = fmaf(s, w.x, z0);
            z1 = fmaf(s, w.y, z1);
        }
    }
}

__device__ __forceinline__ float sigmoidf_(float x) { return 1.0f / (1.0f + expf(-x)); }

template<bool BF16W>
__global__ __launch_bounds__(512)
void lstm_persist(const float* __restrict__ pulse,
                  const float* __restrict__ bn_gamma, const float* __restrict__ bn_beta,
                  const float* __restrict__ bn_mean, const float* __restrict__ bn_var,
                  const float* __restrict__ W_pe, const float* __restrict__ b_pe,
                  const float* __restrict__ embed,
                  const float* __restrict__ W_x, const float* __restrict__ W_h,
                  const float* __restrict__ b_lstm,
                  const float* __restrict__ W_mlp, const float* __restrict__ b_mlp,
                  const float* __restrict__ scale_w, const float* __restrict__ scale_b,
                  const void* __restrict__ WxQ, const void* __restrict__ WhQ,
                  const void* __restrict__ WsQ,
                  float* __restrict__ out) {
    __shared__ float sWpe2[FF * HH];
    __shared__ float sbpe2[HH];
    __shared__ float sbl[H4];
    __shared__ float sWmlp[HH * 2];
    __shared__ float sbuf[HH];
    __shared__ float hbuf[HH];
    __shared__ float cbuf[HH];
    __shared__ float zbuf[H4];
    __shared__ float bnsc[FF], bnsh[FF];
    __shared__ float smisc[6];

    const int tid = threadIdx.x;
    const int bb  = blockIdx.x;

    if (tid < FF) {
        float s = bn_gamma[tid] * rsqrtf(bn_var[tid] + 1e-3f);
        bnsc[tid] = s;
        bnsh[tid] = bn_beta[tid] - bn_mean[tid] * s;
    }
    if (tid < 2) {
        smisc[tid]     = b_mlp[tid];
        smisc[2 + tid] = scale_w[tid];
        smisc[4 + tid] = scale_b[tid];
    }
    for (int i = tid; i < H4; i += 512) sbl[i] = b_lstm[i];
    for (int i = tid; i < 2 * HH; i += 512) sWmlp[i] = W_mlp[i];
    for (int i = tid; i < HH; i += 512) { hbuf[i] = 0.f; cbuf[i] = 0.f; }
    __syncthreads();
    for (int i = tid; i < FF * HH; i += 512) sWpe2[i] = W_pe[i] * bnsc[i / HH];
    for (int i = tid; i < HH; i += 512) {
        float a = b_pe[i];
        #pragma unroll
        for (int f = 0; f < FF; ++f) a = fmaf(bnsh[f], W_pe[f * HH + i], a);
        sbpe2[i] = a;
    }
    __syncthreads();
    if (tid >= HH && tid < 2 * HH) {
        int u = tid - HH;
        const float* pr = pulse + (size_t)bb * TT * FF;
        float acc = sbpe2[u];
        #pragma unroll
        for (int f = 0; f < FF; ++f) acc = fmaf(pr[f], sWpe2[f * HH + u], acc);
        sbuf[u] = acc;
    }
    __syncthreads();

    for (int t = 0; t < TT; ++t) {
        float z0 = sbl[2 * tid], z1 = sbl[2 * tid + 1];
        if constexpr (BF16W) {
            matvec2<true>(WxQ, sbuf, tid, z0, z1);
            matvec2<true>(WhQ, hbuf, tid, z0, z1);
        } else {
            matvec2<false>(W_x, sbuf, tid, z0, z1);
            matvec2<false>(W_h, hbuf, tid, z0, z1);
        }
        zbuf[2 * tid] = z0; zbuf[2 * tid + 1] = z1;
        __syncthreads();
        if (tid < HH) {
            float iv = zbuf[tid], fv = zbuf[tid + HH];
            float gv = zbuf[tid + 2 * HH], ov = zbuf[tid + 3 * HH];
            float c = sigmoidf_(fv) * cbuf[tid] + sigmoidf_(iv) * tanhf(gv);
            cbuf[tid] = c;
            hbuf[tid] = sigmoidf_(ov) * tanhf(c);
        } else if (tid < 2 * HH) {
            int u = tid - HH;
            float acc;
            if (t + 1 < TT) {
                const float* pr = pulse + ((size_t)bb * TT + (t + 1)) * FF;
                acc = sbpe2[u];
                #pragma unroll
                for (int f = 0; f < FF; ++f) acc = fmaf(pr[f], sWpe2[f * HH + u], acc);
            } else {
                acc = embed[u];
            }
            sbuf[u] = acc;
        }
        __syncthreads();
    }

    for (int s = 0; s < DEC; ++s) {
        float z0 = sbl[2 * tid], z1 = sbl[2 * tid + 1];
        if (s == 0) {
            if constexpr (BF16W) {
                matvec2<true>(WxQ, sbuf, tid, z0, z1);
                matvec2<true>(WhQ, hbuf, tid, z0, z1);
            } else {
                matvec2<false>(W_x, sbuf, tid, z0, z1);
                matvec2<false>(W_h, hbuf, tid, z0, z1);
            }
        } else {
            if constexpr (BF16W) {
                matvec2<true>(WsQ, hbuf, tid, z0, z1);
            } else {
                matvec2<false>(W_x, hbuf, tid, z0, z1);
                matvec2<false>(W_h, hbuf, tid, z0, z1);
            }
        }
        zbuf[2 * tid] = z0; zbuf[2 * tid + 1] = z1;
        __syncthreads();
        if (tid < HH) {
            float iv = zbuf[tid], fv = zbuf[tid + HH];
            float gv = zbuf[tid + 2 * HH], ov = zbuf[tid + 3 * HH];
            float c = sigmoidf_(fv) * cbuf[tid] + sigmoidf_(iv) * tanhf(gv);
            cbuf[tid] = c;
            hbuf[tid] = sigmoidf_(ov) * tanhf(c);
        }
        __syncthreads();
        if (tid < 128) {
            int j = tid >> 6, lane = tid & 63;
            float p = 0.f;
            #pragma unroll
            for (int u = lane; u < HH; u += 64) p = fmaf(hbuf[u], sWmlp[u * 2 + j], p);
            p += __shfl_down(p, 32); p += __shfl_down(p, 16); p += __shfl_down(p, 8);
            p += __shfl_down(p, 4);  p += __shfl_down(p, 2);  p += __shfl_down(p, 1);
            if (lane == 0) {
                float pr2 = p + smisc[j];
                out[((size_t)bb * DEC + s) * 2 + j] = pr2 * smisc[2 + j] + smisc[4 + j];
            }
        }
        __syncthreads();
    }
}

extern "C" void kernel_launch(void* const* d_in, const int* in_sizes, int n_in,
                              void* d_out, int out_size, void* d_ws, size_t ws_size,
                              hipStream_t stream) {
    const float* pulse    = (const float*)d_in[0];
    const float* bn_gamma = (const float*)d_in[1];
    const float* bn_beta  = (const float*)d_in[2];
    const float* bn_mean  = (const float*)d_in[3];
    const float* bn_var   = (const float*)d_in[4];
    const float* W_pe     = (const float*)d_in[5];
    const float* b_pe     = (const float*)d_in[6];
    const float* embed    = (const float*)d_in[7];
    const float* W_x      = (const float*)d_in[8];
    const float* W_h      = (const float*)d_in[9];
    const float* b_lstm   = (const float*)d_in[10];
    const float* W_mlp    = (const float*)d_in[11];
    const float* b_mlp    = (const float*)d_in[12];
    const float* scale_w  = (const float*)d_in[13];
    const float* scale_b  = (const float*)d_in[14];
    float* out = (float*)d_out;

    // ws layout:
    //   whf 512K | wsf 512K | wpxf 64K | Wpx32 32K | zbias 4K | zdec0 4K |
    //   hx 256K (16 groups x 16KB h exchange) | ctr 256B
    const size_t SZ_WF   = (size_t)64 * 8 * 64 * 16;     // 524288
    const size_t OFF_WSF = SZ_WF;
    const size_t OFF_PXF = 2 * SZ_WF;                    // 1048576
    const size_t OFF_P32 = OFF_PXF + 65536;
    const size_t OFF_ZB  = OFF_P32 + 32768;
    const size_t OFF_ZD  = OFF_ZB + 4096;
    const size_t OFF_HX  = OFF_ZD + 4096;
    const size_t OFF_CTR = OFF_HX + 262144;
    const size_t needA   = OFF_CTR + 256;

    if (ws_size >= needA) {
        short8v* whf   = (short8v*)d_ws;
        short8v* wsf   = (short8v*)((char*)d_ws + OFF_WSF);
        short8v* wpxf  = (short8v*)((char*)d_ws + OFF_PXF);
        float*   Wpx32 = (float*)((char*)d_ws + OFF_P32);
        float*   zbias = (float*)((char*)d_ws + OFF_ZB);
        float*   zdec0 = (float*)((char*)d_ws + OFF_ZD);
        unsigned short* hx = (unsigned short*)((char*)d_ws + OFF_HX);
        int*     ctr   = (int*)((char*)d_ws + OFF_CTR);

        hipMemsetAsync(ctr, 0, 256, stream);   // zero sync counters each launch/replay
        prep_consts<<<4, 256, 0, stream>>>(W_pe, b_pe, embed, W_x, b_lstm,
                                           bn_gamma, bn_beta, bn_mean, bn_var,
                                           Wpx32, zbias, zdec0);
        prep_wfrag<<<512, 64, 0, stream>>>(W_x, W_h, whf, wsf);
        prep_wpxf<<<64, 64, 0, stream>>>(Wpx32, wpxf);
        // plain launch: grid(64) <= 256 CUs => co-resident by capacity
        lstm_rec12<<<64, 256, 0, stream>>>(whf, wsf, wpxf, pulse,
                                           zbias, zdec0, b_lstm,
                                           W_mlp, b_mlp, scale_w, scale_b,
                                           hx, ctr, out);
        return;
    }

    const size_t NW = (size_t)HH * H4;
    bool use_bf16 = ws_size >= 3 * NW * sizeof(__hip_bfloat16);
    __hip_bfloat16* wxb = (__hip_bfloat16*)d_ws;
    __hip_bfloat16* whb = wxb + NW;
    __hip_bfloat16* wsb = whb + NW;

    if (use_bf16) {
        prep_weights<<<(int)((NW + 255) / 256), 256, 0, stream>>>(W_x, W_h, wxb, whb, wsb);
        lstm_persist<true><<<BB, 512, 0, stream>>>(
            pulse, bn_gamma, bn_beta, bn_mean, bn_var, W_pe, b_pe, embed,
            W_x, W_h, b_lstm, W_mlp, b_mlp, scale_w, scale_b,
            (const void*)wxb, (const void*)whb, (const void*)wsb, out);
    } else {
        lstm_persist<false><<<BB, 512, 0, stream>>>(
            pulse, bn_gamma, bn_beta, bn_mean, bn_var, W_pe, b_pe, embed,
            W_x, W_h, b_lstm, W_mlp, b_mlp, scale_w, scale_b,
            nullptr, nullptr, nullptr, out);
    }
}

// Round 16
// 5406.872 us; speedup vs baseline: 1.3707x; 1.3707x over previous
//
#include <hip/hip_runtime.h>
#include <hip/hip_bf16.h>
#include <hip/hip_fp16.h>
#include <stdint.h>

#define BB  256
#define TT  512
#define FF  8
#define HH  256
#define H4  1024
#define DEC 35
#define NWG 16
#define MW  16

typedef __attribute__((ext_vector_type(8))) short short8v;
typedef __attribute__((ext_vector_type(4))) float f32x4;

// dynamic-LDS layout (bytes)
#define OFF_WPX  0              // zx B-frags: 64 tiles * 64 lanes * 16B = 65536
#define OFF_HHI  65536          // h hi A-frags, 2 buffers * 8192 = 16384
#define OFF_HLO  81920          // h lo A-frags, 2 buffers * 8192 = 16384
#define OFF_MLP  98304          // sWmlp 512 f32 = 2048
#define OFF_SM   100352         // 6 f32 + pad = 32
#define OFF_HB32 100384         // 16*257*4 = 16448 (decoder MLP staging)
#define SMEM_TOT 116832

__device__ __forceinline__ unsigned short f2bf(float x) {
    unsigned u = __float_as_uint(x);
    u += 0x7fffu + ((u >> 16) & 1u);          // RNE
    return (unsigned short)(u >> 16);
}
__device__ __forceinline__ float bf2f(unsigned s) { return __uint_as_float(s << 16); }
__device__ __forceinline__ float sigf(float x) {
    x = fminf(fmaxf(x, -30.f), 30.f);
    return 1.0f / (1.0f + __expf(-x));
}
__device__ __forceinline__ float tanh_(float x) {
    x = fminf(fmaxf(x, -15.f), 15.f);
    float e = __expf(2.0f * x);
    return (e - 1.0f) / (e + 1.0f);
}

// ===================== prep kernels (proven) =====================

__global__ void prep_consts(const float* __restrict__ W_pe, const float* __restrict__ b_pe,
                            const float* __restrict__ embed, const float* __restrict__ W_x,
                            const float* __restrict__ b_lstm,
                            const float* __restrict__ bn_gamma, const float* __restrict__ bn_beta,
                            const float* __restrict__ bn_mean, const float* __restrict__ bn_var,
                            float* __restrict__ Wpx32, float* __restrict__ zbias,
                            float* __restrict__ zdec0) {
    int n = blockIdx.x * 256 + threadIdx.x;
    float acc[FF];
    #pragma unroll
    for (int f = 0; f < FF; ++f) acc[f] = 0.f;
    float bsum = 0.f, dsum = 0.f;
    for (int m = 0; m < HH; ++m) {
        float wx = W_x[m * H4 + n];
        #pragma unroll
        for (int f = 0; f < FF; ++f) acc[f] = fmaf(W_pe[f * HH + m], wx, acc[f]);
        bsum = fmaf(b_pe[m], wx, bsum);
        dsum = fmaf(embed[m], wx, dsum);
    }
    float zb = b_lstm[n] + bsum;
    #pragma unroll
    for (int f = 0; f < FF; ++f) {
        float s  = bn_gamma[f] * rsqrtf(bn_var[f] + 1e-3f);
        float sh = bn_beta[f] - bn_mean[f] * s;
        Wpx32[f * H4 + n] = s * acc[f];
        zb = fmaf(sh, acc[f], zb);
    }
    zbias[n] = zb;
    zdec0[n] = b_lstm[n] + dsum;
}

// B-frags: frag[(nt*8+kc)*64+ln][j] = W[k = kc*32 + 8*(ln>>4) + j][nt*16 + (ln&15)]
__global__ void prep_wfrag(const float* __restrict__ W_x, const float* __restrict__ W_h,
                           short8v* __restrict__ whf, short8v* __restrict__ wsf) {
    int nt = blockIdx.x >> 3, kc = blockIdx.x & 7, ln = threadIdx.x;
    int n = nt * 16 + (ln & 15), q = ln >> 4;
    short8v vh, vs;
    #pragma unroll
    for (int j = 0; j < 8; ++j) {
        int k = kc * 32 + q * 8 + j;
        float wh = W_h[k * H4 + n], wx = W_x[k * H4 + n];
        vh[j] = (short)f2bf(wh);
        vs[j] = (short)f2bf(wx + wh);
    }
    whf[blockIdx.x * 64 + ln] = vh;
    wsf[blockIdx.x * 64 + ln] = vs;
}

// zx B-frags: K=32 packed [Whi|Whi|Wlo|Wlo]; pairs with A=[ph|pl|ph|pl]
// -> one MFMA = (ph+pl)*(Whi+Wlo), fp32-accurate (round-12-proven).
__global__ void prep_wpxf(const float* __restrict__ Wpx32, short8v* __restrict__ wpxf) {
    int nt = blockIdx.x, ln = threadIdx.x;
    int n = nt * 16 + (ln & 15), qq = ln >> 4;
    short8v v;
    #pragma unroll
    for (int j = 0; j < 8; ++j) {
        float wv = Wpx32[j * H4 + n];
        unsigned short hi = f2bf(wv);
        v[j] = (qq < 2) ? (short)hi : (short)f2bf(wv - bf2f(hi));
    }
    wpxf[nt * 64 + ln] = v;
}

// ===================== main recurrent kernel =====================
// ROUND-12 STRUCTURE (best: 5.39ms; MFMA-zx, two 4-tile half-chains, dbl-buf
// split-h, 1 barrier/step) with ONE change: 3-SLICE rolling prefetch in the
// chains (preload kc=0,1,2; refill slot kc%3 with kc+3). Prefetch distance
// goes 1 iter (~80cy) -> 2 iters (~160-240cy) ~= L2 latency, attacking the
// measured ~4us/step exposed-latency gap (serial-sum model 5.9us vs 9.9us
// measured). +16 VGPR (ws 48 + acc 32 + ah/al 8 + misc ~= 108 < 128 budget).
// kc loop fully unrolled so kc%3 indexing is compile-time (no scratch).
// Accumulation order identical -> absmax must repeat 0.0078125.
// [r15 lesson: cross-WG exchange through device scope costs 470MB HBM/L3
//  traffic -- unit-split abandoned; r12 single-WG-per-group retained.]
__global__ __launch_bounds__(512) void lstm_rec13(
    const short8v* __restrict__ whf, const short8v* __restrict__ wsf,
    const short8v* __restrict__ wpxf,
    const float* __restrict__ pulse,
    const float* __restrict__ zbias, const float* __restrict__ zdec0,
    const float* __restrict__ blstm,
    const float* __restrict__ W_mlp, const float* __restrict__ b_mlp,
    const float* __restrict__ scale_w, const float* __restrict__ scale_b,
    float* __restrict__ out) {
    extern __shared__ char smem[];
    short8v* ldsWPX = (short8v*)(smem + OFF_WPX);
    short8v* ldsHI  = (short8v*)(smem + OFF_HHI);   // [buf][kc][ln]
    short8v* ldsLO  = (short8v*)(smem + OFF_HLO);
    float*   sWmlp  = (float*)(smem + OFF_MLP);
    float*   sm     = (float*)(smem + OFF_SM);
    float*   hb32   = (float*)(smem + OFF_HB32);

    const int tid = threadIdx.x, g = blockIdx.x;
    const int w = tid >> 6, ln = tid & 63;
    const int col = ln & 15, q = ln >> 4;

    int ntv[8];
    #pragma unroll
    for (int tl = 0; tl < 8; ++tl) ntv[tl] = (tl >> 1) * 16 + 2 * w + (tl & 1);

    // ---- init ----
    for (int i = tid; i < 64 * 64; i += 512) ldsWPX[i] = wpxf[i];
    {
        short8v zz = {};
        for (int i = tid; i < 2 * 512; i += 512) { ldsHI[i] = zz; ldsLO[i] = zz; }
    }
    for (int i = tid; i < HH * 2; i += 512) sWmlp[i] = W_mlp[i];
    if (tid < 2) { sm[tid] = b_mlp[tid]; sm[2 + tid] = scale_w[tid]; sm[4 + tid] = scale_b[tid]; }

    float zb[8];
    #pragma unroll
    for (int tl = 0; tl < 8; ++tl) zb[tl] = zbias[ntv[tl] * 16 + col];

    float c[8];
    #pragma unroll
    for (int i = 0; i < 8; ++i) c[i] = 0.f;

    // per-lane pulse row pointer: A row = batch = ln&15 (advances 8 floats/step)
    const float* ppt = pulse + ((size_t)(g * MW + (ln & 15)) * TT) * FF;
    const int lohalf = q & 1;   // k-quarters 1,3 carry pulse-lo
    int rb = 0;
    __syncthreads();

    // 4-tile half-chain with 3-SLICE rolling prefetch (48 VGPR buffer)
#define CHAIN4(SRC, TL0) do {                                                   \
        short8v wsb[3][4];                                                      \
        _Pragma("unroll")                                                       \
        for (int s_ = 0; s_ < 3; ++s_)                                          \
            _Pragma("unroll")                                                   \
            for (int i = 0; i < 4; ++i)                                         \
                wsb[s_][i] = (SRC)[(size_t)(ntv[(TL0) + i] * 8 + s_) * 64 + ln];\
        _Pragma("unroll")                                                       \
        for (int kc = 0; kc < 8; ++kc) {                                        \
            const int sl_ = kc % 3;                                             \
            short8v ah = ldsHI[rb * 512 + kc * 64 + ln];                        \
            short8v al = ldsLO[rb * 512 + kc * 64 + ln];                        \
            _Pragma("unroll")                                                   \
            for (int i = 0; i < 4; ++i) {                                       \
                acc[(TL0) + i] = __builtin_amdgcn_mfma_f32_16x16x32_bf16(ah, wsb[sl_][i], acc[(TL0) + i], 0, 0, 0); \
                acc[(TL0) + i] = __builtin_amdgcn_mfma_f32_16x16x32_bf16(al, wsb[sl_][i], acc[(TL0) + i], 0, 0, 0); \
                if (kc + 3 < 8) wsb[sl_][i] = (SRC)[(size_t)(ntv[(TL0) + i] * 8 + kc + 3) * 64 + ln]; \
            }                                                                   \
        }                                                                       \
    } while (0)

#define GATES_WRITE(WITH_HB32) do {                                             \
        unsigned short* hHIs = (unsigned short*)(smem + OFF_HHI) + (rb ^ 1) * 4096; \
        unsigned short* hLOs = (unsigned short*)(smem + OFF_HLO) + (rb ^ 1) * 4096; \
        _Pragma("unroll")                                                       \
        for (int p = 0; p < 2; ++p)                                             \
            _Pragma("unroll")                                                   \
            for (int r = 0; r < 4; ++r) {                                       \
                float cc = sigf(acc[2 + p][r]) * c[p * 4 + r] + sigf(acc[p][r]) * tanh_(acc[4 + p][r]); \
                c[p * 4 + r] = cc;                                              \
                float hh = sigf(acc[6 + p][r]) * tanh_(cc);                     \
                unsigned short hi = f2bf(hh);                                   \
                float lo = hh - bf2f(hi);                                       \
                int ad = w * 512 + (2 * p + (col >> 3)) * 128 + (4 * q + r) * 8 + (col & 7); \
                hHIs[ad] = hi;                                                  \
                hLOs[ad] = f2bf(lo);                                            \
                if (WITH_HB32) hb32[(4 * q + r) * 257 + (32 * w + 16 * p + col)] = hh; \
            }                                                                   \
    } while (0)

    // ---- encoder: 512 steps, ONE barrier each ----
    for (int t = 0; t < TT; ++t) {
        // A-pack: [ph|pl|ph|pl] across k-quarters
        float4 p0 = ((const float4*)ppt)[0];
        float4 p1 = ((const float4*)ppt)[1];
        ppt += FF;
        float pv[8];
        pv[0] = p0.x; pv[1] = p0.y; pv[2] = p0.z; pv[3] = p0.w;
        pv[4] = p1.x; pv[5] = p1.y; pv[6] = p1.z; pv[7] = p1.w;
        short8v apack;
        #pragma unroll
        for (int j = 0; j < 8; ++j) {
            unsigned short hi = f2bf(pv[j]);
            apack[j] = lohalf ? (short)f2bf(pv[j] - bf2f(hi)) : (short)hi;
        }

        // zx: ONE MFMA per tile (B = wpxf in LDS), acc init = zbias
        f32x4 acc[8];
        #pragma unroll
        for (int tl = 0; tl < 8; ++tl) {
            f32x4 av; av[0] = zb[tl]; av[1] = zb[tl]; av[2] = zb[tl]; av[3] = zb[tl];
            short8v bw = ldsWPX[ntv[tl] * 64 + ln];
            acc[tl] = __builtin_amdgcn_mfma_f32_16x16x32_bf16(apack, bw, av, 0, 0, 0);
        }
        CHAIN4(whf, 0);
        CHAIN4(whf, 4);
        GATES_WRITE(0);
        __syncthreads();
        rb ^= 1;
    }

    // ---- decoder: 35 steps ----
    float zd0[8], bl[8];
    #pragma unroll
    for (int tl = 0; tl < 8; ++tl) {
        zd0[tl] = zdec0[ntv[tl] * 16 + col];
        bl[tl]  = blstm[ntv[tl] * 16 + col];
    }

    for (int s = 0; s < DEC; ++s) {
        f32x4 acc[8];
        if (s == 0) {
            #pragma unroll
            for (int tl = 0; tl < 8; ++tl) {
                f32x4 av; av[0] = zd0[tl]; av[1] = zd0[tl]; av[2] = zd0[tl]; av[3] = zd0[tl];
                acc[tl] = av;
            }
            CHAIN4(whf, 0);
            CHAIN4(whf, 4);
        } else {
            #pragma unroll
            for (int tl = 0; tl < 8; ++tl) {
                f32x4 av; av[0] = bl[tl]; av[1] = bl[tl]; av[2] = bl[tl]; av[3] = bl[tl];
                acc[tl] = av;
            }
            CHAIN4(wsf, 0);
            CHAIN4(wsf, 4);
        }
        GATES_WRITE(1);
        __syncthreads();

        // MLP head: pred = h@W_mlp + b_mlp; eis = pred*sw + sb
        {
            int m = tid >> 5, j = (tid >> 4) & 1, uc = tid & 15;
            float p2 = 0.f;
            #pragma unroll
            for (int i = 0; i < 16; ++i) {
                int u = i * 16 + uc;
                p2 = fmaf(hb32[m * 257 + u], sWmlp[u * 2 + j], p2);
            }
            p2 += __shfl_down(p2, 8, 16);
            p2 += __shfl_down(p2, 4, 16);
            p2 += __shfl_down(p2, 2, 16);
            p2 += __shfl_down(p2, 1, 16);
            if (uc == 0) {
                float pr = p2 + sm[j];
                out[((size_t)(g * MW + m) * DEC + s) * 2 + j] = pr * sm[2 + j] + sm[4 + j];
            }
        }
        __syncthreads();
        rb ^= 1;
    }
#undef CHAIN4
#undef GATES_WRITE
}

// ===================== fallback (round-2, proven) =====================
__global__ void prep_weights(const float* __restrict__ Wx, const float* __restrict__ Wh,
                             __hip_bfloat16* __restrict__ wxb,
                             __hip_bfloat16* __restrict__ whb,
                             __hip_bfloat16* __restrict__ wsb) {
    int i = blockIdx.x * 256 + threadIdx.x;
    if (i < HH * H4) {
        float x = Wx[i], h = Wh[i];
        wxb[i] = __float2bfloat16(x);
        whb[i] = __float2bfloat16(h);
        wsb[i] = __float2bfloat16(x + h);
    }
}

template<bool BF16W>
__device__ __forceinline__ void matvec2(const void* __restrict__ W,
                                        const float* __restrict__ vec,
                                        int tid, float& z0, float& z1) {
    if constexpr (BF16W) {
        const uint32_t* Wp = (const uint32_t*)W;
        #pragma unroll 8
        for (int k = 0; k < HH; ++k) {
            uint32_t w = Wp[(size_t)k * (H4 / 2) + tid];
            float s = vec[k];
            union { uint32_t u; float f; } lo, hi;
            lo.u = w << 16;
            hi.u = w & 0xffff0000u;
            z0 = fmaf(s, lo.f, z0);
            z1 = fmaf(s, hi.f, z1);
        }
    } else {
        const float2* Wp = (const float2*)W;
        #pragma unroll 8
        for (int k = 0; k < HH; ++k) {
            float2 w = Wp[(size_t)k * (H4 / 2) + tid];
            float s = vec[k];
            z0 = fmaf(s, w.x, z0);
            z1 = fmaf(s, w.y, z1);
        }
    }
}

__device__ __forceinline__ float sigmoidf_(float x) { return 1.0f / (1.0f + expf(-x)); }

template<bool BF16W>
__global__ __launch_bounds__(512)
void lstm_persist(const float* __restrict__ pulse,
                  const float* __restrict__ bn_gamma, const float* __restrict__ bn_beta,
                  const float* __restrict__ bn_mean, const float* __restrict__ bn_var,
                  const float* __restrict__ W_pe, const float* __restrict__ b_pe,
                  const float* __restrict__ embed,
                  const float* __restrict__ W_x, const float* __restrict__ W_h,
                  const float* __restrict__ b_lstm,
                  const float* __restrict__ W_mlp, const float* __restrict__ b_mlp,
                  const float* __restrict__ scale_w, const float* __restrict__ scale_b,
                  const void* __restrict__ WxQ, const void* __restrict__ WhQ,
                  const void* __restrict__ WsQ,
                  float* __restrict__ out) {
    __shared__ float sWpe2[FF * HH];
    __shared__ float sbpe2[HH];
    __shared__ float sbl[H4];
    __shared__ float sWmlp[HH * 2];
    __shared__ float sbuf[HH];
    __shared__ float hbuf[HH];
    __shared__ float cbuf[HH];
    __shared__ float zbuf[H4];
    __shared__ float bnsc[FF], bnsh[FF];
    __shared__ float smisc[6];

    const int tid = threadIdx.x;
    const int bb  = blockIdx.x;

    if (tid < FF) {
        float s = bn_gamma[tid] * rsqrtf(bn_var[tid] + 1e-3f);
        bnsc[tid] = s;
        bnsh[tid] = bn_beta[tid] - bn_mean[tid] * s;
    }
    if (tid < 2) {
        smisc[tid]     = b_mlp[tid];
        smisc[2 + tid] = scale_w[tid];
        smisc[4 + tid] = scale_b[tid];
    }
    for (int i = tid; i < H4; i += 512) sbl[i] = b_lstm[i];
    for (int i = tid; i < 2 * HH; i += 512) sWmlp[i] = W_mlp[i];
    for (int i = tid; i < HH; i += 512) { hbuf[i] = 0.f; cbuf[i] = 0.f; }
    __syncthreads();
    for (int i = tid; i < FF * HH; i += 512) sWpe2[i] = W_pe[i] * bnsc[i / HH];
    for (int i = tid; i < HH; i += 512) {
        float a = b_pe[i];
        #pragma unroll
        for (int f = 0; f < FF; ++f) a = fmaf(bnsh[f], W_pe[f * HH + i], a);
        sbpe2[i] = a;
    }
    __syncthreads();
    if (tid >= HH && tid < 2 * HH) {
        int u = tid - HH;
        const float* pr = pulse + (size_t)bb * TT * FF;
        float acc = sbpe2[u];
        #pragma unroll
        for (int f = 0; f < FF; ++f) acc = fmaf(pr[f], sWpe2[f * HH + u], acc);
        sbuf[u] = acc;
    }
    __syncthreads();

    for (int t = 0; t < TT; ++t) {
        float z0 = sbl[2 * tid], z1 = sbl[2 * tid + 1];
        if constexpr (BF16W) {
            matvec2<true>(WxQ, sbuf, tid, z0, z1);
            matvec2<true>(WhQ, hbuf, tid, z0, z1);
        } else {
            matvec2<false>(W_x, sbuf, tid, z0, z1);
            matvec2<false>(W_h, hbuf, tid, z0, z1);
        }
        zbuf[2 * tid] = z0; zbuf[2 * tid + 1] = z1;
        __syncthreads();
        if (tid < HH) {
            float iv = zbuf[tid], fv = zbuf[tid + HH];
            float gv = zbuf[tid + 2 * HH], ov = zbuf[tid + 3 * HH];
            float c = sigmoidf_(fv) * cbuf[tid] + sigmoidf_(iv) * tanhf(gv);
            cbuf[tid] = c;
            hbuf[tid] = sigmoidf_(ov) * tanhf(c);
        } else if (tid < 2 * HH) {
            int u = tid - HH;
            float acc;
            if (t + 1 < TT) {
                const float* pr = pulse + ((size_t)bb * TT + (t + 1)) * FF;
                acc = sbpe2[u];
                #pragma unroll
                for (int f = 0; f < FF; ++f) acc = fmaf(pr[f], sWpe2[f * HH + u], acc);
            } else {
                acc = embed[u];
            }
            sbuf[u] = acc;
        }
        __syncthreads();
    }

    for (int s = 0; s < DEC; ++s) {
        float z0 = sbl[2 * tid], z1 = sbl[2 * tid + 1];
        if (s == 0) {
            if constexpr (BF16W) {
                matvec2<true>(WxQ, sbuf, tid, z0, z1);
                matvec2<true>(WhQ, hbuf, tid, z0, z1);
            } else {
                matvec2<false>(W_x, sbuf, tid, z0, z1);
                matvec2<false>(W_h, hbuf, tid, z0, z1);
            }
        } else {
            if constexpr (BF16W) {
                matvec2<true>(WsQ, hbuf, tid, z0, z1);
            } else {
                matvec2<false>(W_x, hbuf, tid, z0, z1);
                matvec2<false>(W_h, hbuf, tid, z0, z1);
            }
        }
        zbuf[2 * tid] = z0; zbuf[2 * tid + 1] = z1;
        __syncthreads();
        if (tid < HH) {
            float iv = zbuf[tid], fv = zbuf[tid + HH];
            float gv = zbuf[tid + 2 * HH], ov = zbuf[tid + 3 * HH];
            float c = sigmoidf_(fv) * cbuf[tid] + sigmoidf_(iv) * tanhf(gv);
            cbuf[tid] = c;
            hbuf[tid] = sigmoidf_(ov) * tanhf(c);
        }
        __syncthreads();
        if (tid < 128) {
            int j = tid >> 6, lane = tid & 63;
            float p = 0.f;
            #pragma unroll
            for (int u = lane; u < HH; u += 64) p = fmaf(hbuf[u], sWmlp[u * 2 + j], p);
            p += __shfl_down(p, 32); p += __shfl_down(p, 16); p += __shfl_down(p, 8);
            p += __shfl_down(p, 4);  p += __shfl_down(p, 2);  p += __shfl_down(p, 1);
            if (lane == 0) {
                float pr2 = p + smisc[j];
                out[((size_t)bb * DEC + s) * 2 + j] = pr2 * smisc[2 + j] + smisc[4 + j];
            }
        }
        __syncthreads();
    }
}

extern "C" void kernel_launch(void* const* d_in, const int* in_sizes, int n_in,
                              void* d_out, int out_size, void* d_ws, size_t ws_size,
                              hipStream_t stream) {
    const float* pulse    = (const float*)d_in[0];
    const float* bn_gamma = (const float*)d_in[1];
    const float* bn_beta  = (const float*)d_in[2];
    const float* bn_mean  = (const float*)d_in[3];
    const float* bn_var   = (const float*)d_in[4];
    const float* W_pe     = (const float*)d_in[5];
    const float* b_pe     = (const float*)d_in[6];
    const float* embed    = (const float*)d_in[7];
    const float* W_x      = (const float*)d_in[8];
    const float* W_h      = (const float*)d_in[9];
    const float* b_lstm   = (const float*)d_in[10];
    const float* W_mlp    = (const float*)d_in[11];
    const float* b_mlp    = (const float*)d_in[12];
    const float* scale_w  = (const float*)d_in[13];
    const float* scale_b  = (const float*)d_in[14];
    float* out = (float*)d_out;

    // ws layout: whf 512K | wsf 512K | wpxf 64K | Wpx32 32K | zbias 4K | zdec0 4K
    const size_t SZ_WF   = (size_t)64 * 8 * 64 * 16;     // 524288
    const size_t SZ_PXF  = (size_t)64 * 64 * 16;         // 65536
    const size_t SZ_PX32 = (size_t)FF * H4 * 4;          // 32768
    const size_t needA = 2 * SZ_WF + SZ_PXF + SZ_PX32 + 2 * (size_t)H4 * 4;

    if (ws_size >= needA) {
        short8v* whf   = (short8v*)d_ws;
        short8v* wsf   = (short8v*)((char*)d_ws + SZ_WF);
        short8v* wpxf  = (short8v*)((char*)d_ws + 2 * SZ_WF);
        float*   Wpx32 = (float*)((char*)d_ws + 2 * SZ_WF + SZ_PXF);
        float*   zbias = Wpx32 + FF * H4;
        float*   zdec0 = zbias + H4;

        hipFuncSetAttribute((const void*)lstm_rec13,
                            hipFuncAttributeMaxDynamicSharedMemorySize, SMEM_TOT);

        prep_consts<<<4, 256, 0, stream>>>(W_pe, b_pe, embed, W_x, b_lstm,
                                           bn_gamma, bn_beta, bn_mean, bn_var,
                                           Wpx32, zbias, zdec0);
        prep_wfrag<<<512, 64, 0, stream>>>(W_x, W_h, whf, wsf);
        prep_wpxf<<<64, 64, 0, stream>>>(Wpx32, wpxf);
        lstm_rec13<<<NWG, 512, SMEM_TOT, stream>>>(whf, wsf, wpxf, pulse,
                                                   zbias, zdec0, b_lstm,
                                                   W_mlp, b_mlp, scale_w, scale_b, out);
        return;
    }

    const size_t NW = (size_t)HH * H4;
    bool use_bf16 = ws_size >= 3 * NW * sizeof(__hip_bfloat16);
    __hip_bfloat16* wxb = (__hip_bfloat16*)d_ws;
    __hip_bfloat16* whb = wxb + NW;
    __hip_bfloat16* wsb = whb + NW;

    if (use_bf16) {
        prep_weights<<<(int)((NW + 255) / 256), 256, 0, stream>>>(W_x, W_h, wxb, whb, wsb);
        lstm_persist<true><<<BB, 512, 0, stream>>>(
            pulse, bn_gamma, bn_beta, bn_mean, bn_var, W_pe, b_pe, embed,
            W_x, W_h, b_lstm, W_mlp, b_mlp, scale_w, scale_b,
            (const void*)wxb, (const void*)whb, (const void*)wsb, out);
    } else {
        lstm_persist<false><<<BB, 512, 0, stream>>>(
            pulse, bn_gamma, bn_beta, bn_mean, bn_var, W_pe, b_pe, embed,
            W_x, W_h, b_lstm, W_mlp, b_mlp, scale_w, scale_b,
            nullptr, nullptr, nullptr, out);
    }
}